// Round 10
// baseline (238.017 us; speedup 1.0000x reference)
//
#include <hip/hip_runtime.h>

typedef unsigned short u16;
typedef unsigned int   u32;
typedef __bf16 bf16x8 __attribute__((ext_vector_type(8)));
typedef __bf16 bf16x2 __attribute__((ext_vector_type(2)));
typedef float  f32x4  __attribute__((ext_vector_type(4)));
typedef float  f32x2  __attribute__((ext_vector_type(2)));

#define DEV static __device__ __forceinline__
#define NEG_INF (-__builtin_inff())

DEV u16 f2bf(float f) {
  u32 u = __builtin_bit_cast(u32, f);
  u += 0x7fffu + ((u >> 16) & 1u);
  return (u16)(u >> 16);
}

DEV float bf2f(u16 v) {
  u32 u = (u32)v << 16;
  return __builtin_bit_cast(float, u);
}

DEV u32 packbf(float a, float b) {
  f32x2 v = {a, b};
  bf16x2 r = __builtin_convertvector(v, bf16x2);
  return __builtin_bit_cast(u32, r);
}

typedef __attribute__((address_space(1))) void gvoid_t;
typedef __attribute__((address_space(3))) void svoid_t;

DEV void async16(const void* g, void* l) {
  __builtin_amdgcn_global_load_lds((gvoid_t*)g, (svoid_t*)l, 16, 0, 0);
}

DEV f32x4 mfma_bf16(bf16x8 a, bf16x8 b, f32x4 c) {
  return __builtin_amdgcn_mfma_f32_16x16x32_bf16(a, b, c, 0, 0, 0);
}

#define SBAR() __builtin_amdgcn_sched_barrier(0)
#define BARRIER() do { SBAR(); __builtin_amdgcn_s_barrier(); SBAR(); } while (0)
#define LGK0() do { asm volatile("s_waitcnt lgkmcnt(0)" ::: "memory"); SBAR(); } while (0)
#define LGKC(n) do { asm volatile("s_waitcnt lgkmcnt(" #n ")" ::: "memory"); SBAR(); } while (0)
#define VMC(n) do { asm volatile("s_waitcnt vmcnt(" #n ")" ::: "memory"); SBAR(); } while (0)

// ---------------- elementwise converts ----------------
__global__ void cvt_bf16_k(const float* __restrict__ s, u16* __restrict__ d, int n4) {
  int i = blockIdx.x * blockDim.x + threadIdx.x;
  if (i >= n4) return;
  float4 v = ((const float4*)s)[i];
  ((ushort4*)d)[i] = make_ushort4(f2bf(v.x), f2bf(v.y), f2bf(v.z), f2bf(v.w));
}

// build interleaved w13: dst [5632][1024] bf16; 16-row blocks alternate w1/w3
__global__ void w13_prep_k(const float* __restrict__ w1, const float* __restrict__ w3,
                           u16* __restrict__ d, int n4) {
  int i = blockIdx.x * blockDim.x + threadIdx.x;
  if (i >= n4) return;
  int e = i * 4;
  int r = e >> 10;
  int c = e & 1023;
  int blk = r >> 4, j = r & 15;
  int srow = (blk >> 1) * 16 + j;
  ushort4 o = make_ushort4(0, 0, 0, 0);
  if (srow < 2730) {
    const float* src = (blk & 1) ? w3 : w1;
    float4 v = *(const float4*)&src[(size_t)srow * 1024 + c];
    o = make_ushort4(f2bf(v.x), f2bf(v.y), f2bf(v.z), f2bf(v.w));
  }
  ((ushort4*)d)[i] = o;
}

// pad cols: src [R][Cs] -> dst [R][Cd] bf16, cols >= Cs zero
__global__ void pad_cols_k(const float* __restrict__ s, u16* __restrict__ d,
                           int Cs, int Cd, int n4) {
  int i = blockIdx.x * blockDim.x + threadIdx.x;
  if (i >= n4) return;
  int e = i * 4;
  int r = e / Cd;
  int c = e - r * Cd;
  u16 o[4];
#pragma unroll
  for (int j = 0; j < 4; ++j) {
    int cc = c + j;
    o[j] = (cc < Cs) ? f2bf(s[(size_t)r * Cs + cc]) : (u16)0;
  }
  ((ushort4*)d)[i] = make_ushort4(o[0], o[1], o[2], o[3]);
}

// ---------------- rmsnorm (D=1024) -> bf16 ----------------
__global__ void rmsnorm_cvt_k(const float* __restrict__ in, const float* __restrict__ w,
                              u16* __restrict__ out) {
  __shared__ float red[4];
  int row = blockIdx.x;
  int t = threadIdx.x;
  const float4 v = ((const float4*)(in + (size_t)row * 1024))[t];
  float ss = v.x * v.x + v.y * v.y + v.z * v.z + v.w * v.w;
#pragma unroll
  for (int off = 1; off < 64; off <<= 1) ss += __shfl_xor(ss, off);
  if ((t & 63) == 0) red[t >> 6] = ss;
  __syncthreads();
  float tot = red[0] + red[1] + red[2] + red[3];
  float rs = rsqrtf(tot * (1.0f / 1024.0f) + 1e-6f);
  const float4 wv = ((const float4*)w)[t];
  ((ushort4*)(out + (size_t)row * 1024))[t] =
      make_ushort4(f2bf(v.x * rs * wv.x), f2bf(v.y * rs * wv.y),
                   f2bf(v.z * rs * wv.z), f2bf(v.w * rs * wv.w));
}

// ---------------- q/k rmsnorm + rope (bf16 qkv input) ----------------
__global__ void qk_post_k(const u16* __restrict__ qkv, const float* __restrict__ qw,
                          const float* __restrict__ kw, u16* __restrict__ Qb,
                          u16* __restrict__ Kb) {
  int g = blockIdx.x * 4 + (threadIdx.x >> 6);
  int d = threadIdx.x & 63;
  int b = g >> 15;
  int r = g & 32767;
  int s = r >> 4;
  int h = r & 15;
  size_t base = ((size_t)(b * 2048 + s)) * 3072 + h * 64 + d;
  float qv = bf2f(qkv[base]);
  float kv = bf2f(qkv[base + 1024]);
  float q2 = qv * qv, k2 = kv * kv;
#pragma unroll
  for (int off = 1; off < 64; off <<= 1) {
    q2 += __shfl_xor(q2, off);
    k2 += __shfl_xor(k2, off);
  }
  float qn = qv * rsqrtf(q2 * (1.0f / 64.0f) + 1e-6f) * qw[d];
  float kn = kv * rsqrtf(k2 * (1.0f / 64.0f) + 1e-6f) * kw[d];
  int j = d & 31;
  float invf = __expf((float)j * -0.28782313662425572f);
  float ang = (float)s * invf;
  float sn, cs;
  sincosf(ang, &sn, &cs);
  float pq = __shfl_xor(qn, 32);
  float pk = __shfl_xor(kn, 32);
  float qo = (d < 32) ? (qn * cs - pq * sn) : (qn * cs + pq * sn);
  float ko = (d < 32) ? (kn * cs - pk * sn) : (kn * cs + pk * sn);
  size_t ob = ((size_t)((b * 16 + h) * 2048 + s)) * 64 + d;
  Qb[ob] = f2bf(qo);
  Kb[ob] = f2bf(ko);
}

// ---------------- V transpose (bf16 qkv input) ----------------
__global__ void vtrans_k(const u16* __restrict__ qkv, u16* __restrict__ VT) {
  __shared__ u16 tile[64][65];
  int bh = blockIdx.y;
  int b = bh >> 4, h = bh & 15;
  int s0 = blockIdx.x * 64;
  int t = threadIdx.x;
  int tx = t & 63, ty = t >> 6;
#pragma unroll
  for (int p = 0; p < 16; ++p) {
    int sl = p * 4 + ty;
    tile[sl][tx] = qkv[((size_t)(b * 2048 + s0 + sl)) * 3072 + 2048 + h * 64 + tx];
  }
  __syncthreads();
#pragma unroll
  for (int p = 0; p < 16; ++p) {
    int dl = p * 4 + ty;
    VT[((size_t)(bh * 64 + dl)) * 2048 + s0 + tx] = tile[tx][dl];
  }
}

// ---------------- 128^2 pipelined GEMM: C = A*B^T (+res) [R6-proven body] ----------------
template <int EPI>
__global__ __launch_bounds__(256, 1) void gemm128p(
    const u16* __restrict__ A, const u16* __restrict__ B0,
    const float* __restrict__ res, void* __restrict__ outp, int M, int N, int K, int NT) {
  __shared__ u16 S[49152];
  const int tid = threadIdx.x;
  const int lane = tid & 63;
  const int wv = tid >> 6;
  const int wr = wv >> 1;
  const int wc = wv & 1;
  const int c16 = lane & 15, g4 = lane >> 4;

  const int gx = gridDim.x;
  const int nwg = gx * gridDim.y;
  const int lin = blockIdx.x + gx * blockIdx.y;
  const int swz = (lin & 7) * (nwg >> 3) + (lin >> 3);
  const int bm = (swz / gx) * 128;
  const int bn = (swz % gx) * 128;

  const int strow = tid >> 3;
  const int stcs = ((tid & 7) ^ (strow & 7)) * 8;
  const u16* Ap = A + (size_t)(bm + strow) * K + stcs;
  const u16* Bp = B0 + (size_t)(bn + strow) * K + stcs;
  const int wvb = wv * 512;

#define STG(bufi, t) do { const size_t _o = (size_t)(t) * 64; _Pragma("unroll") \
    for (int s = 0; s < 4; ++s) { \
      async16(Ap + _o + (size_t)s * 32 * K, &S[(bufi) * 16384 + s * 2048 + wvb]); \
      async16(Bp + _o + (size_t)s * 32 * K, &S[(bufi) * 16384 + 8192 + s * 2048 + wvb]); \
    } } while (0)

  f32x4 acc[4][4] = {};
  const int xk0 = (g4 ^ (c16 & 7)) * 8;
  const int xk1 = ((4 + g4) ^ (c16 & 7)) * 8;
  const int arb = (wr * 64 + c16) * 64;
  const int brb = 8192 + (wc * 64 + c16) * 64;

  STG(0, 0);
  STG(1, 1);
  VMC(8); BARRIER();

  int cur = 0;
  for (int kt = 0; kt < NT; ++kt) {
    int n2 = cur + 2; if (n2 >= 3) n2 -= 3;
    if (kt + 2 < NT) {
      if (n2 == 0) STG(0, kt + 2);
      else if (n2 == 1) STG(1, kt + 2);
      else STG(2, kt + 2);
    }
    bf16x8 a[4][2], b[4][2];
    const int cb = cur * 16384;
#pragma unroll
    for (int mf = 0; mf < 4; ++mf) {
      a[mf][0] = *(const bf16x8*)&S[cb + arb + mf * 1024 + xk0];
      a[mf][1] = *(const bf16x8*)&S[cb + arb + mf * 1024 + xk1];
    }
#pragma unroll
    for (int nf = 0; nf < 4; ++nf) {
      b[nf][0] = *(const bf16x8*)&S[cb + brb + nf * 1024 + xk0];
      b[nf][1] = *(const bf16x8*)&S[cb + brb + nf * 1024 + xk1];
    }
    LGK0();
    __builtin_amdgcn_s_setprio(1);
#pragma unroll
    for (int ks = 0; ks < 2; ++ks)
#pragma unroll
      for (int mf = 0; mf < 4; ++mf)
#pragma unroll
        for (int nf = 0; nf < 4; ++nf)
          acc[mf][nf] = mfma_bf16(a[mf][ks], b[nf][ks], acc[mf][nf]);
    __builtin_amdgcn_s_setprio(0);
    if (kt + 2 < NT) { VMC(8); } else { VMC(0); }
    BARRIER();
    cur = cur + 1; if (cur >= 3) cur = 0;
  }

#pragma unroll
  for (int mf = 0; mf < 4; ++mf)
#pragma unroll
    for (int nf = 0; nf < 4; ++nf) {
      int row = bm + wr * 64 + mf * 16 + g4 * 4;
      int col = bn + wc * 64 + nf * 16 + c16;
#pragma unroll
      for (int r = 0; r < 4; ++r) {
        size_t idx = (size_t)(row + r) * (size_t)N + col;
        if constexpr (EPI == 1) {
          ((float*)outp)[idx] = res[idx] + acc[mf][nf][r];
        } else {
          ((u16*)outp)[idx] = f2bf(acc[mf][nf][r]);
        }
      }
    }
#undef STG
}

// ---------------- 256x192 4-phase GEMM (QKV), overlapped reads ----------------
// ds_reads of each fragment issued one phase ahead / after last consumer;
// counted lgkmcnt; 2 barriers per K-step; staging into fully-dead buf at ph3.
__global__ __launch_bounds__(512, 1) void gemm192(
    const u16* __restrict__ A, const u16* __restrict__ B0,
    u16* __restrict__ outp, int N, int K, int NT) {
  __shared__ u16 SA[32768];   // 2 buf x [half][ks][128][32]
  __shared__ u16 SB[24576];   // 2 buf x [192][64] swizzled
  const int tid = threadIdx.x;
  const int lane = tid & 63;
  const int wv = tid >> 6;
  const int wr = wv >> 2;
  const int wc = wv & 3;
  const int c16 = lane & 15, g4 = lane >> 4;

  const int gx = gridDim.x;
  const int nwg = gx * gridDim.y;
  const int lin = blockIdx.x + gx * blockIdx.y;
  const int swz = (lin & 7) * (nwg >> 3) + (lin >> 3);
  const int bm = (swz / gx) * 256;
  const int bn = (swz % gx) * 192;

  const int sr = tid >> 2;
  const int sc2s = ((tid & 3) * 16) ^ (((sr >> 3) & 1) << 5);
  const int scol = sc2s >> 1;
  const u16* Asrc = A + (size_t)(bm + sr) * K + scol;
  const int ldst = wv * 512;
  const int brow = tid >> 3;
  const int bgr = (tid & 7) ^ (brow & 7);
  const u16* Bsrc = B0 + (size_t)(bn + brow) * K + bgr * 8;
  const int bldst = wv * 512;

#define STA_(buf, h, t) do { \
    const u16* _g = Asrc + (size_t)(h) * 128 * K + (t) * 64; \
    async16(_g,      &SA[(buf) * 16384 + (h) * 8192 + ldst]); \
    async16(_g + 32, &SA[(buf) * 16384 + (h) * 8192 + 4096 + ldst]); } while (0)
#define STB_(buf, p, t) do { \
    async16(Bsrc + (size_t)(p) * 64 * K + (t) * 64, \
            &SB[(buf) * 12288 + (p) * 4096 + bldst]); } while (0)

  const int xr = (g4 * 8) ^ (((c16 >> 3) & 1) << 4);
  const int raOff = c16 * 32 + xr;
  const int abase0 = wr * 8192;
  const int brow0 = wc * 48 + c16;
  const int bsw = c16 & 7;

#define LDA_(buf, qm) do { _Pragma("unroll") \
    for (int mf = 0; mf < 4; ++mf) { \
      int _ro = (buf) * 16384 + abase0 + ((qm) * 64 + mf * 16) * 32 + raOff; \
      a[mf][0] = *(const bf16x8*)&SA[_ro]; \
      a[mf][1] = *(const bf16x8*)&SA[_ro + 4096]; } } while (0)
#define LDB01_(buf) do { _Pragma("unroll") \
    for (int nf = 0; nf < 2; ++nf) { \
      int _r = (buf) * 12288 + (brow0 + nf * 16) * 64; \
      bq01[nf][0] = *(const bf16x8*)&SB[_r + ((g4) ^ bsw) * 8]; \
      bq01[nf][1] = *(const bf16x8*)&SB[_r + ((4 + g4) ^ bsw) * 8]; } } while (0)
#define LDB2_(buf) do { \
      int _r = (buf) * 12288 + (brow0 + 32) * 64; \
      bq2[0] = *(const bf16x8*)&SB[_r + ((g4) ^ bsw) * 8]; \
      bq2[1] = *(const bf16x8*)&SB[_r + ((4 + g4) ^ bsw) * 8]; } while (0)
#define MM16(qm) do { _Pragma("unroll") \
    for (int mf = 0; mf < 4; ++mf) _Pragma("unroll") \
      for (int nf = 0; nf < 2; ++nf) { \
        acc[(qm) * 4 + mf][nf] = mfma_bf16(a[mf][0], bq01[nf][0], acc[(qm) * 4 + mf][nf]); \
        acc[(qm) * 4 + mf][nf] = mfma_bf16(a[mf][1], bq01[nf][1], acc[(qm) * 4 + mf][nf]); } } while (0)
#define MM8(qm) do { _Pragma("unroll") \
    for (int mf = 0; mf < 4; ++mf) { \
      acc[(qm) * 4 + mf][2] = mfma_bf16(a[mf][0], bq2[0], acc[(qm) * 4 + mf][2]); \
      acc[(qm) * 4 + mf][2] = mfma_bf16(a[mf][1], bq2[1], acc[(qm) * 4 + mf][2]); } } while (0)

  f32x4 acc[8][3] = {};
  bf16x8 a[4][2], bq01[2][2], bq2[2];

  // prologue: stage t0 (7 loads) -> buf0, t1 (7 loads) -> buf1; read kt0 ph1 frags
  STB_(0, 0, 0); STB_(0, 1, 0); STB_(0, 2, 0); STA_(0, 0, 0); STA_(0, 1, 0);
  STB_(1, 0, 1); STB_(1, 1, 1); STB_(1, 2, 1); STA_(1, 0, 1); STA_(1, 1, 1);
  VMC(7); BARRIER();
  LDA_(0, 0); LDB01_(0);          // 12 reads outstanding

  for (int kt = 0; kt < NT; ++kt) {
    const int buf = kt & 1, nbuf = buf ^ 1;
    const int t2 = (kt + 2 < NT) ? kt + 2 : NT - 1;
    // ph1: issue bq2 (2 reads); wait aA+bq01; MFMA q(0,01)
    LDB2_(buf);
    LGKC(2);
    __builtin_amdgcn_s_setprio(1); MM16(0); __builtin_amdgcn_s_setprio(0);
    SBAR();
    // ph2: wait bq2; MFMA q(0,2); reload a <- A-half1 (overlaps MM8 exec)
    LGK0();
    __builtin_amdgcn_s_setprio(1); MM8(0); __builtin_amdgcn_s_setprio(0);
    SBAR();
    LDA_(buf, 1);
    // ph3: all reads of buf done -> barrier -> stage t+2 into dead buf; MFMA q(1,01)
    LGK0();
    BARRIER();
    STB_(buf, 0, t2); STB_(buf, 1, t2); STB_(buf, 2, t2);
    STA_(buf, 0, t2); STA_(buf, 1, t2);
    __builtin_amdgcn_s_setprio(1); MM16(1); __builtin_amdgcn_s_setprio(0);
    SBAR();
    // ph4: t+1 tile landed; issue next-kt reads around MFMA q(1,2)
    VMC(7);
    BARRIER();
    LDB01_(nbuf);
    __builtin_amdgcn_s_setprio(1); MM8(1); __builtin_amdgcn_s_setprio(0);
    SBAR();
    LDA_(nbuf, 0);
  }
  asm volatile("s_waitcnt vmcnt(0) lgkmcnt(0)" ::: "memory");

#pragma unroll
  for (int mf = 0; mf < 8; ++mf) {
    int row0 = bm + wr * 128 + mf * 16 + g4 * 4;
#pragma unroll
    for (int nf = 0; nf < 3; ++nf) {
      int col = bn + wc * 48 + nf * 16 + c16;
#pragma unroll
      for (int r = 0; r < 4; ++r)
        outp[(size_t)(row0 + r) * N + col] = f2bf(acc[mf][nf][r]);
    }
  }
#undef STA_
#undef STB_
#undef LDA_
#undef LDB01_
#undef LDB2_
#undef MM16
#undef MM8
}

// ---------------- 256^2 4-phase GEMM, overlapped reads ----------------
template <int QM, int QN>
DEV void mmq(f32x4 (&acc)[8][4], const bf16x8 (&a)[4][2], const bf16x8 (&b)[2][2]) {
#pragma unroll
  for (int mf = 0; mf < 4; ++mf)
#pragma unroll
    for (int nf = 0; nf < 2; ++nf) {
      acc[QM * 4 + mf][QN * 2 + nf] = mfma_bf16(a[mf][0], b[nf][0], acc[QM * 4 + mf][QN * 2 + nf]);
      acc[QM * 4 + mf][QN * 2 + nf] = mfma_bf16(a[mf][1], b[nf][1], acc[QM * 4 + mf][QN * 2 + nf]);
    }
}

template <int EPI>
__global__ __launch_bounds__(512, 2) void gemm256(
    const u16* __restrict__ A, const u16* __restrict__ B0,
    void* __restrict__ outp, int M, int N, int K, int NT) {
  __shared__ u16 S[65536];
  const int tid = threadIdx.x;
  const int lane = tid & 63;
  const int wv = tid >> 6;
  const int wr = wv >> 2;
  const int wc = wv & 3;
  const int c16 = lane & 15, g4 = lane >> 4;

  int gx = gridDim.x;
  int nwg = gx * gridDim.y;
  int lin = blockIdx.x + gx * blockIdx.y;
  int swz = ((nwg & 7) == 0) ? ((lin & 7) * (nwg >> 3) + (lin >> 3)) : lin;
  const int bm = (swz / gx) * 256;
  const int bn = (swz % gx) * 256;

  const int sr = tid >> 2;
  const int sc2s = ((tid & 3) * 16) ^ (((sr >> 3) & 1) << 5);
  const int scol = sc2s >> 1;
  const u16* Asrc = A + (size_t)(bm + sr) * K + scol;
  const u16* Bsrc = B0 + (size_t)(bn + sr) * K + scol;
  const int ldst = wv * 512;

#define STA(buf, h, t) do { \
    const u16* _g = Asrc + (size_t)(h) * 128 * K + (t) * 64; \
    async16(_g,      &S[(buf) * 16384 + (h) * 8192 + ldst]); \
    async16(_g + 32, &S[(buf) * 16384 + (h) * 8192 + 4096 + ldst]); } while (0)
#define STB(buf, h, t) do { \
    const u16* _g = Bsrc + (size_t)(h) * 128 * K + (t) * 64; \
    async16(_g,      &S[32768 + (buf) * 16384 + (h) * 8192 + ldst]); \
    async16(_g + 32, &S[32768 + (buf) * 16384 + (h) * 8192 + 4096 + ldst]); } while (0)

  const int xr = (g4 * 8) ^ (((c16 >> 3) & 1) << 4);
  const int raOff = c16 * 32 + xr;
  const int abase0 = wr * 8192;
  const int bbase0 = 32768 + (wc >> 1) * 8192 + (wc & 1) * 2048;

#define LDA(buf, qm) do { _Pragma("unroll") \
    for (int mf = 0; mf < 4; ++mf) { \
      int _ro = (buf) * 16384 + abase0 + ((qm) * 64 + mf * 16) * 32 + raOff; \
      a[mf][0] = *(const bf16x8*)&S[_ro]; \
      a[mf][1] = *(const bf16x8*)&S[_ro + 4096]; } } while (0)
#define LDB(buf, qn, bq) do { _Pragma("unroll") \
    for (int nf = 0; nf < 2; ++nf) { \
      int _ro = (buf) * 16384 + bbase0 + ((qn) * 2 + nf) * 512 + raOff; \
      bq[nf][0] = *(const bf16x8*)&S[_ro]; \
      bq[nf][1] = *(const bf16x8*)&S[_ro + 4096]; } } while (0)

  f32x4 acc[8][4] = {};
  bf16x8 a[4][2], bq0[2][2], bq1[2][2];

  // prologue: stage t0 + t1 (16 loads); read kt0 ph1 fragments
  STB(0, 0, 0); STB(0, 1, 0); STA(0, 0, 0); STA(0, 1, 0);
  STB(1, 0, 1); STB(1, 1, 1); STA(1, 0, 1); STA(1, 1, 1);
  VMC(8); BARRIER();
  LDA(0, 0); LDB(0, 0, bq0);      // 12 reads outstanding

  for (int kt = 0; kt < NT; ++kt) {
    const int buf = kt & 1, nbuf = buf ^ 1;
    const int t2 = (kt + 2 < NT) ? kt + 2 : NT - 1;
    // ph1: issue bq1 (4 reads); wait a+bq0; MFMA q(0,0)
    LDB(buf, 1, bq1);
    LGKC(4);
    __builtin_amdgcn_s_setprio(1); mmq<0, 0>(acc, a, bq0); __builtin_amdgcn_s_setprio(0);
    SBAR();
    // ph2: wait bq1; MFMA q(0,1); reload a <- A-half1 (overlaps exec)
    LGK0();
    __builtin_amdgcn_s_setprio(1); mmq<0, 1>(acc, a, bq1); __builtin_amdgcn_s_setprio(0);
    SBAR();
    LDA(buf, 1);
    // ph3: all reads of buf complete -> barrier -> stage t+2 into dead buf; MFMA q(1,0)
    LGK0();
    BARRIER();
    STB(buf, 0, t2); STB(buf, 1, t2);
    STA(buf, 0, t2); STA(buf, 1, t2);
    __builtin_amdgcn_s_setprio(1); mmq<1, 0>(acc, a, bq0); __builtin_amdgcn_s_setprio(0);
    SBAR();
    // ph4: t+1 tile landed; issue next-kt reads around MFMA q(1,1)
    VMC(8);
    BARRIER();
    LDB(nbuf, 0, bq0);
    __builtin_amdgcn_s_setprio(1); mmq<1, 1>(acc, a, bq1); __builtin_amdgcn_s_setprio(0);
    SBAR();
    LDA(nbuf, 0);
  }
  asm volatile("s_waitcnt vmcnt(0) lgkmcnt(0)" ::: "memory");

#pragma unroll
  for (int mf = 0; mf < 8; ++mf) {
    int row0 = bm + wr * 128 + mf * 16 + g4 * 4;
    if constexpr (EPI == 0) {
#pragma unroll
      for (int nf = 0; nf < 4; ++nf) {
        int col = bn + wc * 64 + nf * 16 + c16;
#pragma unroll
        for (int r = 0; r < 4; ++r)
          ((float*)outp)[(size_t)(row0 + r) * N + col] = acc[mf][nf][r];
      }
    } else {
      const int NH = N >> 1;
#pragma unroll
      for (int p = 0; p < 2; ++p) {
        int hid = ((bn + wc * 64) >> 1) + p * 16 + c16;
#pragma unroll
        for (int r = 0; r < 4; ++r) {
          float gg = acc[mf][2 * p][r];
          float uu = acc[mf][2 * p + 1][r];
          ((u16*)outp)[(size_t)(row0 + r) * NH + hid] = f2bf(gg * uu / (1.0f + __expf(-gg)));
        }
      }
    }
  }
#undef STA
#undef STB
#undef LDA
#undef LDB
}

// ---------------- flash attention, sliding window 512 [R6-proven body] ----------------
__global__ __launch_bounds__(256, 4) void attn_k(const u16* __restrict__ Q,
                                                 const u16* __restrict__ Kb,
                                                 const u16* __restrict__ VT,
                                                 u16* __restrict__ O) {
  __shared__ u16 KT[2 * 2048];
  __shared__ u16 VTl[2 * 2048];
  __shared__ float bsm[4][16];
  __shared__ u16 Plds[4][16 * 40];
  const int tid = threadIdx.x;
  const int lane = tid & 63;
  const int wv = tid >> 6;
  const int bh = blockIdx.y;
  const int q0b = blockIdx.x * 64;
  const int q0 = q0b + wv * 16;
  const int c16 = lane & 15;
  const int hi = lane >> 4;
  const u16* Qp = Q + ((size_t)bh * 2048 + q0) * 64;

  const bf16x8 qf0 = *(const bf16x8*)&Qp[c16 * 64 + hi * 8];
  const bf16x8 qf1 = *(const bf16x8*)&Qp[c16 * 64 + 32 + hi * 8];

  const int krow = tid >> 3;
  const int kcs = ((tid & 7) ^ (krow & 7)) * 8;
  const u16* Ksrc = Kb + (size_t)bh * 131072 + (size_t)krow * 64 + kcs;
  const int vrow = tid >> 2;
  const int vcs = ((tid & 3) ^ ((vrow >> 1) & 3)) * 8;
  const u16* Vsrc = VT + (size_t)bh * 131072 + (size_t)vrow * 2048 + vcs;
  const int wvb = wv * 512;

  f32x4 o[4] = {};
  float m = -30.0f;
  float psum = 0.0f;
  const float SCL = 0.125f * 1.4426950408889634f;
  int startb = q0b - 511;
  if (startb < 0) startb = 0;
  startb &= ~31;
  const int kgend = q0b + 32;
  u16* Pw = Plds[wv];
  float* bw = bsm[wv];

  const int xh0 = (hi ^ (c16 & 7)) * 8;
  const int xh4 = ((4 + hi) ^ (c16 & 7)) * 8;
  const int xv = (hi ^ ((c16 >> 1) & 3)) * 8;

  async16(Ksrc + (size_t)startb * 64, &KT[wvb]);
  async16(Vsrc + startb, &VTl[wvb]);

  int buf = 0;
  for (int kg = startb; kg <= kgend; kg += 32) {
    if (kg + 32 <= kgend) {
      async16(Ksrc + (size_t)(kg + 32) * 64, &KT[(buf ^ 1) * 2048 + wvb]);
      async16(Vsrc + (kg + 32), &VTl[(buf ^ 1) * 2048 + wvb]);
      VMC(2);
    } else {
      VMC(0);
    }
    BARRIER();
    if (kg <= q0 + 15 && kg >= q0 - 542) {
      const int kb = buf * 2048 + c16 * 64;
      bf16x8 k00 = *(const bf16x8*)&KT[kb + xh0];
      bf16x8 k01 = *(const bf16x8*)&KT[kb + xh4];
      bf16x8 k10 = *(const bf16x8*)&KT[kb + 1024 + xh0];
      bf16x8 k11 = *(const bf16x8*)&KT[kb + 1024 + xh4];
      bf16x8 vf[4];
#pragma unroll
      for (int n = 0; n < 4; ++n)
        vf[n] = *(const bf16x8*)&VTl[buf * 2048 + (n * 16 + c16) * 32 + xv];
      LGK0();

      f32x4 slo = {0.f, 0.f, 0.f, 0.f}, shi2 = {0.f, 0.f, 0.f, 0.f};
      __builtin_amdgcn_s_setprio(1);
      slo = mfma_bf16(k00, qf0, slo);
      slo = mfma_bf16(k01, qf1, slo);
      shi2 = mfma_bf16(k10, qf0, shi2);
      shi2 = mfma_bf16(k11, qf1, shi2);
      __builtin_amdgcn_s_setprio(0);

      float sc[8];
#pragma unroll
      for (int r = 0; r < 4; ++r) {
        sc[r] = slo[r] * SCL;
        sc[4 + r] = shi2[r] * SCL;
      }
      const bool inter = (kg + 31 <= q0) && (kg >= q0 - 496);
      if (!inter) {
        const int row = q0 + c16;
#pragma unroll
        for (int r = 0; r < 4; ++r) {
          int col = kg + hi * 4 + r;
          if (!(col <= row && col > row - 512)) sc[r] = -1e30f;
          int col2 = col + 16;
          if (!(col2 <= row && col2 > row - 512)) sc[4 + r] = -1e30f;
        }
      }
      float tmax = fmaxf(fmaxf(fmaxf(sc[0], sc[1]), fmaxf(sc[2], sc[3])),
                         fmaxf(fmaxf(sc[4], sc[5]), fmaxf(sc[6], sc[7])));
      tmax = fmaxf(tmax, __shfl_xor(tmax, 16));
      tmax = fmaxf(tmax, __shfl_xor(tmax, 32));
      if (__any(tmax > m + 8.0f)) {
        float mn = fmaxf(m, tmax);
        float corr = exp2f(m - mn);
        m = mn;
        psum *= corr;
        bw[c16] = corr;
        __builtin_amdgcn_wave_barrier();
        float cr[4];
#pragma unroll
        for (int r = 0; r < 4; ++r) cr[r] = bw[hi * 4 + r];
        __builtin_amdgcn_wave_barrier();
#pragma unroll
        for (int n = 0; n < 4; ++n)
#pragma unroll
          for (int r = 0; r < 4; ++r) o[n][r] *= cr[r];
      }
      float p[8];
#pragma unroll
      for (int i = 0; i < 8; ++i) p[i] = exp2f(sc[i] - m);
      psum += ((p[0] + p[1]) + (p[2] + p[3])) + ((p[4] + p[5]) + (p[6] + p[7]));

      uint2 wlo, whi2;
      wlo.x = packbf(p[0], p[1]);
      wlo.y = packbf(p[2], p[3]);
      whi2.x = packbf(p[4], p[5]);
      whi2.y = packbf(p[6], p[7]);
      *(uint2*)&Pw[c16 * 40 + hi * 4] = wlo;
      *(uint2*)&Pw[c16 * 40 + 16 + hi * 4] = whi2;
      __builtin_amdgcn_wave_barrier();
      bf16x8 pa = *(const bf16x8*)&Pw[c16 * 40 + hi * 8];
      __builtin_amdgcn_wave_barrier();
      __builtin_amdgcn_s_setprio(1);
#pragma unroll
      for (int n = 0; n < 4; ++n) o[n] = mfma_bf16(pa, vf[n], o[n]);
      __builtin_amdgcn_s_setprio(0);
    }
    BARRIER();
    buf ^= 1;
  }

  psum += __shfl_xor(psum, 16);
  psum += __shfl_xor(psum, 32);
  bw[c16] = psum;
  __builtin_amdgcn_wave_barrier();
  const int b = bh >> 4, h = bh & 15;
#pragma unroll
  for (int r = 0; r < 4; ++r) {
    float inv = 1.0f / bw[hi * 4 + r];
    int row = q0 + hi * 4 + r;
#pragma unroll
    for (int n = 0; n < 4; ++n)
      O[((size_t)(b * 2048 + row)) * 1024 + h * 64 + n * 16 + c16] = f2bf(o[n][r] * inv);
  }
}

// ---------------- host ----------------
extern "C" void kernel_launch(void* const* d_in, const int* in_sizes, int n_in,
                              void* d_out, int out_size, void* d_ws, size_t ws_size,
                              hipStream_t stream) {
  const float* x    = (const float*)d_in[0];
  const float* n1w  = (const float*)d_in[1];
  const float* n2w  = (const float*)d_in[2];
  const float* wqkv = (const float*)d_in[3];
  const float* qnw  = (const float*)d_in[4];
  const float* knw  = (const float*)d_in[5];
  const float* wo   = (const float*)d_in[6];
  const float* w1   = (const float*)d_in[7];
  const float* w3   = (const float*)d_in[8];
  const float* w2   = (const float*)d_in[9];
  float* out = (float*)d_out;
  char* ws = (char*)d_ws;

  u16*   wqkv_b = (u16*)(ws + 0);            // 6291456 B
  u16*   wo_b   = (u16*)(ws + 6291456);      // 2097152
  u16*   w13i   = (u16*)(ws + 8388608);      // 11534336  [5632][1024] interleaved
  u16*   w2p    = (u16*)(ws + 19922944);     // 5767168   [1024][2816]
  u16*   h_b    = (u16*)(ws + 25690112);     // 8388608   (aliased: attn out bf16)
  u16*   qkv_b  = (u16*)(ws + 34078720);     // 25165824  bf16 [4096][3072] (aliased: act_b)
  u16*   act_b  = (u16*)(ws + 34078720);     // 23068672  bf16 [4096][2816]
  u16*   Qb     = (u16*)(ws + 84410368);     // 8388608   (aliased: h2 bf16)
  u16*   Kb     = (u16*)(ws + 92798976);     // 8388608
  u16*   VTb    = (u16*)(ws + 101187584);    // 8388608
  float* x2f    = (float*)(ws + 109576192);  // 16777216 ; total 126353408
  u16*   attn_b = h_b;
  u16*   h2_b   = Qb;

  // weight prep
  cvt_bf16_k<<<3072, 256, 0, stream>>>(wqkv, wqkv_b, 786432);
  cvt_bf16_k<<<1024, 256, 0, stream>>>(wo, wo_b, 262144);
  w13_prep_k<<<5632, 256, 0, stream>>>(w1, w3, w13i, 1441792);
  pad_cols_k<<<2816, 256, 0, stream>>>(w2, w2p, 2730, 2816, 720896);

  // h = rmsnorm(x) -> bf16
  rmsnorm_cvt_k<<<4096, 256, 0, stream>>>(x, n1w, h_b);
  // qkv = h @ w_qkv^T -> bf16, 256x192 full-chip grid
  gemm192<<<dim3(16, 16), 512, 0, stream>>>(h_b, wqkv_b, qkv_b, 3072, 1024, 16);
  // q/k rmsnorm + rope ; V transpose
  qk_post_k<<<16384, 256, 0, stream>>>(qkv_b, qnw, knw, Qb, Kb);
  vtrans_k<<<dim3(32, 32), 256, 0, stream>>>(qkv_b, VTb);
  // attention
  attn_k<<<dim3(32, 32), 256, 0, stream>>>(Qb, Kb, VTb, attn_b);
  // x2 = x + attn @ w_o^T  -- pipelined 128^2
  gemm128p<1><<<dim3(8, 32), 256, 0, stream>>>(attn_b, wo_b, x, x2f, 4096, 1024, 1024, 16);
  // h2 = rmsnorm(x2) -> bf16
  rmsnorm_cvt_k<<<4096, 256, 0, stream>>>(x2f, n2w, h2_b);
  // act = silu(g)*u via interleaved single-B 256^2 GEMM (overlapped reads)
  gemm256<3><<<dim3(22, 16), 512, 0, stream>>>(h2_b, w13i, act_b, 4096, 5632, 1024, 16);
  // out = x2 + act @ w2^T  -- pipelined 128^2
  gemm128p<1><<<dim3(8, 32), 256, 0, stream>>>(act_b, w2p, x2f, out, 4096, 1024, 2816, 44);
}

// Round 11
// 225.521 us; speedup vs baseline: 1.0554x; 1.0554x over previous
//
#include <hip/hip_runtime.h>

typedef unsigned short u16;
typedef unsigned int   u32;
typedef __bf16 bf16x8 __attribute__((ext_vector_type(8)));
typedef __bf16 bf16x2 __attribute__((ext_vector_type(2)));
typedef float  f32x4  __attribute__((ext_vector_type(4)));
typedef float  f32x2  __attribute__((ext_vector_type(2)));

#define DEV static __device__ __forceinline__
#define NEG_INF (-__builtin_inff())

DEV u16 f2bf(float f) {
  u32 u = __builtin_bit_cast(u32, f);
  u += 0x7fffu + ((u >> 16) & 1u);
  return (u16)(u >> 16);
}

DEV float bf2f(u16 v) {
  u32 u = (u32)v << 16;
  return __builtin_bit_cast(float, u);
}

DEV u32 packbf(float a, float b) {
  f32x2 v = {a, b};
  bf16x2 r = __builtin_convertvector(v, bf16x2);
  return __builtin_bit_cast(u32, r);
}

typedef __attribute__((address_space(1))) void gvoid_t;
typedef __attribute__((address_space(3))) void svoid_t;

DEV void async16(const void* g, void* l) {
  __builtin_amdgcn_global_load_lds((gvoid_t*)g, (svoid_t*)l, 16, 0, 0);
}

DEV f32x4 mfma_bf16(bf16x8 a, bf16x8 b, f32x4 c) {
  return __builtin_amdgcn_mfma_f32_16x16x32_bf16(a, b, c, 0, 0, 0);
}

#define SBAR() __builtin_amdgcn_sched_barrier(0)
#define BARRIER() do { SBAR(); __builtin_amdgcn_s_barrier(); SBAR(); } while (0)
#define LGK0() do { asm volatile("s_waitcnt lgkmcnt(0)" ::: "memory"); SBAR(); } while (0)
#define VMC(n) do { asm volatile("s_waitcnt vmcnt(" #n ")" ::: "memory"); SBAR(); } while (0)

// ---------------- elementwise converts ----------------
__global__ void cvt_bf16_k(const float* __restrict__ s, u16* __restrict__ d, int n4) {
  int i = blockIdx.x * blockDim.x + threadIdx.x;
  if (i >= n4) return;
  float4 v = ((const float4*)s)[i];
  ((ushort4*)d)[i] = make_ushort4(f2bf(v.x), f2bf(v.y), f2bf(v.z), f2bf(v.w));
}

// build interleaved w13: dst [5632][1024] bf16; 16-row blocks alternate w1/w3
__global__ void w13_prep_k(const float* __restrict__ w1, const float* __restrict__ w3,
                           u16* __restrict__ d, int n4) {
  int i = blockIdx.x * blockDim.x + threadIdx.x;
  if (i >= n4) return;
  int e = i * 4;
  int r = e >> 10;
  int c = e & 1023;
  int blk = r >> 4, j = r & 15;
  int srow = (blk >> 1) * 16 + j;
  ushort4 o = make_ushort4(0, 0, 0, 0);
  if (srow < 2730) {
    const float* src = (blk & 1) ? w3 : w1;
    float4 v = *(const float4*)&src[(size_t)srow * 1024 + c];
    o = make_ushort4(f2bf(v.x), f2bf(v.y), f2bf(v.z), f2bf(v.w));
  }
  ((ushort4*)d)[i] = o;
}

// pad cols: src [R][Cs] -> dst [R][Cd] bf16, cols >= Cs zero
__global__ void pad_cols_k(const float* __restrict__ s, u16* __restrict__ d,
                           int Cs, int Cd, int n4) {
  int i = blockIdx.x * blockDim.x + threadIdx.x;
  if (i >= n4) return;
  int e = i * 4;
  int r = e / Cd;
  int c = e - r * Cd;
  u16 o[4];
#pragma unroll
  for (int j = 0; j < 4; ++j) {
    int cc = c + j;
    o[j] = (cc < Cs) ? f2bf(s[(size_t)r * Cs + cc]) : (u16)0;
  }
  ((ushort4*)d)[i] = make_ushort4(o[0], o[1], o[2], o[3]);
}

// ---------------- rmsnorm (D=1024) -> bf16 ----------------
__global__ void rmsnorm_cvt_k(const float* __restrict__ in, const float* __restrict__ w,
                              u16* __restrict__ out) {
  __shared__ float red[4];
  int row = blockIdx.x;
  int t = threadIdx.x;
  const float4 v = ((const float4*)(in + (size_t)row * 1024))[t];
  float ss = v.x * v.x + v.y * v.y + v.z * v.z + v.w * v.w;
#pragma unroll
  for (int off = 1; off < 64; off <<= 1) ss += __shfl_xor(ss, off);
  if ((t & 63) == 0) red[t >> 6] = ss;
  __syncthreads();
  float tot = red[0] + red[1] + red[2] + red[3];
  float rs = rsqrtf(tot * (1.0f / 1024.0f) + 1e-6f);
  const float4 wv = ((const float4*)w)[t];
  ((ushort4*)(out + (size_t)row * 1024))[t] =
      make_ushort4(f2bf(v.x * rs * wv.x), f2bf(v.y * rs * wv.y),
                   f2bf(v.z * rs * wv.z), f2bf(v.w * rs * wv.w));
}

// ---------------- q/k rmsnorm + rope (bf16 qkv input) ----------------
__global__ void qk_post_k(const u16* __restrict__ qkv, const float* __restrict__ qw,
                          const float* __restrict__ kw, u16* __restrict__ Qb,
                          u16* __restrict__ Kb) {
  int g = blockIdx.x * 4 + (threadIdx.x >> 6);
  int d = threadIdx.x & 63;
  int b = g >> 15;
  int r = g & 32767;
  int s = r >> 4;
  int h = r & 15;
  size_t base = ((size_t)(b * 2048 + s)) * 3072 + h * 64 + d;
  float qv = bf2f(qkv[base]);
  float kv = bf2f(qkv[base + 1024]);
  float q2 = qv * qv, k2 = kv * kv;
#pragma unroll
  for (int off = 1; off < 64; off <<= 1) {
    q2 += __shfl_xor(q2, off);
    k2 += __shfl_xor(k2, off);
  }
  float qn = qv * rsqrtf(q2 * (1.0f / 64.0f) + 1e-6f) * qw[d];
  float kn = kv * rsqrtf(k2 * (1.0f / 64.0f) + 1e-6f) * kw[d];
  int j = d & 31;
  float invf = __expf((float)j * -0.28782313662425572f);
  float ang = (float)s * invf;
  float sn, cs;
  sincosf(ang, &sn, &cs);
  float pq = __shfl_xor(qn, 32);
  float pk = __shfl_xor(kn, 32);
  float qo = (d < 32) ? (qn * cs - pq * sn) : (qn * cs + pq * sn);
  float ko = (d < 32) ? (kn * cs - pk * sn) : (kn * cs + pk * sn);
  size_t ob = ((size_t)((b * 16 + h) * 2048 + s)) * 64 + d;
  Qb[ob] = f2bf(qo);
  Kb[ob] = f2bf(ko);
}

// ---------------- V transpose (bf16 qkv input) ----------------
__global__ void vtrans_k(const u16* __restrict__ qkv, u16* __restrict__ VT) {
  __shared__ u16 tile[64][65];
  int bh = blockIdx.y;
  int b = bh >> 4, h = bh & 15;
  int s0 = blockIdx.x * 64;
  int t = threadIdx.x;
  int tx = t & 63, ty = t >> 6;
#pragma unroll
  for (int p = 0; p < 16; ++p) {
    int sl = p * 4 + ty;
    tile[sl][tx] = qkv[((size_t)(b * 2048 + s0 + sl)) * 3072 + 2048 + h * 64 + tx];
  }
  __syncthreads();
#pragma unroll
  for (int p = 0; p < 16; ++p) {
    int dl = p * 4 + ty;
    VT[((size_t)(bh * 64 + dl)) * 2048 + s0 + tx] = tile[tx][dl];
  }
}

// ---------------- 128^2 pipelined GEMM, 8 waves (2/SIMD): C = A*B^T (+res) ----------------
// Triple-buffered LDS (3 x 32KB), BK=64, 2-tiles-ahead staging, counted vmcnt(4).
// Wave w: rows [wr*32,+32) (wr=w>>1), cols [wc*64,+64) (wc=w&1); acc[2][4].
// EPI 1: f32 store + residual. EPI 2: bf16 store.
template <int EPI>
__global__ __launch_bounds__(512, 1) void gemm128p(
    const u16* __restrict__ A, const u16* __restrict__ B0,
    const float* __restrict__ res, void* __restrict__ outp, int M, int N, int K, int NT) {
  __shared__ u16 S[49152];
  const int tid = threadIdx.x;
  const int lane = tid & 63;
  const int wv = tid >> 6;
  const int wr = wv >> 1;
  const int wc = wv & 1;
  const int c16 = lane & 15, g4 = lane >> 4;

  const int gx = gridDim.x;
  const int nwg = gx * gridDim.y;
  const int lin = blockIdx.x + gx * blockIdx.y;
  const int swz = (lin & 7) * (nwg >> 3) + (lin >> 3);
  const int bm = (swz / gx) * 128;
  const int bn = (swz % gx) * 128;

  // staging: shot covers 64 rows (512 threads x 16B); row = tid>>3, chunk (tid&7)^(row&7)
  const int strow = tid >> 3;
  const int stcs = ((tid & 7) ^ (strow & 7)) * 8;
  const u16* Ap = A + (size_t)(bm + strow) * K + stcs;
  const u16* Bp = B0 + (size_t)(bn + strow) * K + stcs;
  const int wvb = wv * 512;           // wave-uniform dest (elems), spans 0..4095

#define STG(bufi, t) do { const size_t _o = (size_t)(t) * 64; \
      async16(Ap + _o,                    &S[(bufi) * 16384 +         wvb]); \
      async16(Ap + _o + (size_t)64 * K,   &S[(bufi) * 16384 +  4096 + wvb]); \
      async16(Bp + _o,                    &S[(bufi) * 16384 +  8192 + wvb]); \
      async16(Bp + _o + (size_t)64 * K,   &S[(bufi) * 16384 + 12288 + wvb]); \
    } while (0)

  f32x4 acc[2][4] = {};
  const int xk0 = (g4 ^ (c16 & 7)) * 8;
  const int xk1 = ((4 + g4) ^ (c16 & 7)) * 8;
  const int arb = (wr * 32 + c16) * 64;
  const int brb = 8192 + (wc * 64 + c16) * 64;

  STG(0, 0);
  STG(1, 1);
  VMC(4); BARRIER();

  int cur = 0;
  for (int kt = 0; kt < NT; ++kt) {
    int n2 = cur + 2; if (n2 >= 3) n2 -= 3;
    if (kt + 2 < NT) {
      if (n2 == 0) STG(0, kt + 2);
      else if (n2 == 1) STG(1, kt + 2);
      else STG(2, kt + 2);
    }
    bf16x8 a[2][2], b[4][2];
    const int cb = cur * 16384;
#pragma unroll
    for (int mf = 0; mf < 2; ++mf) {
      a[mf][0] = *(const bf16x8*)&S[cb + arb + mf * 1024 + xk0];
      a[mf][1] = *(const bf16x8*)&S[cb + arb + mf * 1024 + xk1];
    }
#pragma unroll
    for (int nf = 0; nf < 4; ++nf) {
      b[nf][0] = *(const bf16x8*)&S[cb + brb + nf * 1024 + xk0];
      b[nf][1] = *(const bf16x8*)&S[cb + brb + nf * 1024 + xk1];
    }
    LGK0();
    __builtin_amdgcn_s_setprio(1);
#pragma unroll
    for (int ks = 0; ks < 2; ++ks)
#pragma unroll
      for (int mf = 0; mf < 2; ++mf)
#pragma unroll
        for (int nf = 0; nf < 4; ++nf)
          acc[mf][nf] = mfma_bf16(a[mf][ks], b[nf][ks], acc[mf][nf]);
    __builtin_amdgcn_s_setprio(0);
    if (kt + 2 < NT) { VMC(4); } else { VMC(0); }
    BARRIER();
    cur = cur + 1; if (cur >= 3) cur = 0;
  }

#pragma unroll
  for (int mf = 0; mf < 2; ++mf)
#pragma unroll
    for (int nf = 0; nf < 4; ++nf) {
      int row = bm + wr * 32 + mf * 16 + g4 * 4;
      int col = bn + wc * 64 + nf * 16 + c16;
#pragma unroll
      for (int r = 0; r < 4; ++r) {
        size_t idx = (size_t)(row + r) * (size_t)N + col;
        if constexpr (EPI == 1) {
          ((float*)outp)[idx] = res[idx] + acc[mf][nf][r];
        } else {
          ((u16*)outp)[idx] = f2bf(acc[mf][nf][r]);
        }
      }
    }
#undef STG
}

// ---------------- 256x192 4-phase GEMM (QKV) [R6-proven body] ----------------
__global__ __launch_bounds__(512, 1) void gemm192(
    const u16* __restrict__ A, const u16* __restrict__ B0,
    u16* __restrict__ outp, int N, int K, int NT) {
  __shared__ u16 SA[32768];   // 2 buf x [half][ks][128][32]
  __shared__ u16 SB[24576];   // 2 buf x [192][64] swizzled
  const int tid = threadIdx.x;
  const int lane = tid & 63;
  const int wv = tid >> 6;
  const int wr = wv >> 2;
  const int wc = wv & 3;
  const int c16 = lane & 15, g4 = lane >> 4;

  const int gx = gridDim.x;
  const int nwg = gx * gridDim.y;
  const int lin = blockIdx.x + gx * blockIdx.y;
  const int swz = (lin & 7) * (nwg >> 3) + (lin >> 3);
  const int bm = (swz / gx) * 256;
  const int bn = (swz % gx) * 192;

  const int sr = tid >> 2;
  const int sc2s = ((tid & 3) * 16) ^ (((sr >> 3) & 1) << 5);
  const int scol = sc2s >> 1;
  const u16* Asrc = A + (size_t)(bm + sr) * K + scol;
  const int ldst = wv * 512;
  const int brow = tid >> 3;
  const int bgr = (tid & 7) ^ (brow & 7);
  const u16* Bsrc = B0 + (size_t)(bn + brow) * K + bgr * 8;
  const int bldst = wv * 512;

#define STA_(buf, h, t) do { \
    const u16* _g = Asrc + (size_t)(h) * 128 * K + (t) * 64; \
    async16(_g,      &SA[(buf) * 16384 + (h) * 8192 + ldst]); \
    async16(_g + 32, &SA[(buf) * 16384 + (h) * 8192 + 4096 + ldst]); } while (0)
#define STB_(buf, p, t) do { \
    async16(Bsrc + (size_t)(p) * 64 * K + (t) * 64, \
            &SB[(buf) * 12288 + (p) * 4096 + bldst]); } while (0)

  const int xr = (g4 * 8) ^ (((c16 >> 3) & 1) << 4);
  const int raOff = c16 * 32 + xr;
  const int abase0 = wr * 8192;
  const int brow0 = wc * 48 + c16;
  const int bsw = c16 & 7;

#define LDA_(buf, qm) do { _Pragma("unroll") \
    for (int mf = 0; mf < 4; ++mf) { \
      int _ro = (buf) * 16384 + abase0 + ((qm) * 64 + mf * 16) * 32 + raOff; \
      a[mf][0] = *(const bf16x8*)&SA[_ro]; \
      a[mf][1] = *(const bf16x8*)&SA[_ro + 4096]; } } while (0)
#define LDB01_(buf) do { _Pragma("unroll") \
    for (int nf = 0; nf < 2; ++nf) { \
      int _r = (buf) * 12288 + (brow0 + nf * 16) * 64; \
      bq01[nf][0] = *(const bf16x8*)&SB[_r + ((g4) ^ bsw) * 8]; \
      bq01[nf][1] = *(const bf16x8*)&SB[_r + ((4 + g4) ^ bsw) * 8]; } } while (0)
#define LDB2_(buf) do { \
      int _r = (buf) * 12288 + (brow0 + 32) * 64; \
      bq2[0] = *(const bf16x8*)&SB[_r + ((g4) ^ bsw) * 8]; \
      bq2[1] = *(const bf16x8*)&SB[_r + ((4 + g4) ^ bsw) * 8]; } while (0)
#define MM16(qm) do { _Pragma("unroll") \
    for (int mf = 0; mf < 4; ++mf) _Pragma("unroll") \
      for (int nf = 0; nf < 2; ++nf) { \
        acc[(qm) * 4 + mf][nf] = mfma_bf16(a[mf][0], bq01[nf][0], acc[(qm) * 4 + mf][nf]); \
        acc[(qm) * 4 + mf][nf] = mfma_bf16(a[mf][1], bq01[nf][1], acc[(qm) * 4 + mf][nf]); } } while (0)
#define MM8(qm) do { _Pragma("unroll") \
    for (int mf = 0; mf < 4; ++mf) { \
      acc[(qm) * 4 + mf][2] = mfma_bf16(a[mf][0], bq2[0], acc[(qm) * 4 + mf][2]); \
      acc[(qm) * 4 + mf][2] = mfma_bf16(a[mf][1], bq2[1], acc[(qm) * 4 + mf][2]); } } while (0)

  f32x4 acc[8][3] = {};
  bf16x8 a[4][2], bq01[2][2], bq2[2];

  // prologue: t0 full (7 shots) -> buf0; t1: B0,B1,A0 (4 shots) -> buf1
  STB_(0, 0, 0); STB_(0, 1, 0); STB_(0, 2, 0); STA_(0, 0, 0); STA_(0, 1, 0);
  STB_(1, 0, 1); STB_(1, 1, 1); STA_(1, 0, 1);
  VMC(4); BARRIER();

  for (int kt = 0; kt < NT; ++kt) {
    const int buf = kt & 1, ob = buf ^ 1;
    const int t1 = (kt + 1 < NT) ? kt + 1 : NT - 1;
    const int t2 = (kt + 2 < NT) ? kt + 2 : NT - 1;
    // ph1: stage B2(t+1) -> ob
    LDA_(buf, 0); LDB01_(buf);
    STB_(ob, 2, t1);
    BARRIER(); LGK0();
    __builtin_amdgcn_s_setprio(1); MM16(0); __builtin_amdgcn_s_setprio(0);
    BARRIER();
    // ph2: stage A-h1(t+1) -> ob
    LDB2_(buf);
    STA_(ob, 1, t1);
    BARRIER(); LGK0();
    __builtin_amdgcn_s_setprio(1); MM8(0); __builtin_amdgcn_s_setprio(0);
    BARRIER();
    // ph3: stage B0,B1(t+2) -> buf (B dead after ph2)
    LDA_(buf, 1);
    STB_(buf, 0, t2); STB_(buf, 1, t2);
    BARRIER(); LGK0();
    __builtin_amdgcn_s_setprio(1); MM16(1); __builtin_amdgcn_s_setprio(0);
    BARRIER();
    // ph4: stage A-h0(t+2) -> buf (A dead after ph3)
    STA_(buf, 0, t2);
    BARRIER();
    __builtin_amdgcn_s_setprio(1); MM8(1); __builtin_amdgcn_s_setprio(0);
    VMC(4); BARRIER();
  }
  asm volatile("s_waitcnt vmcnt(0)" ::: "memory");

#pragma unroll
  for (int mf = 0; mf < 8; ++mf) {
    int row0 = bm + wr * 128 + mf * 16 + g4 * 4;
#pragma unroll
    for (int nf = 0; nf < 3; ++nf) {
      int col = bn + wc * 48 + nf * 16 + c16;
#pragma unroll
      for (int r = 0; r < 4; ++r)
        outp[(size_t)(row0 + r) * N + col] = f2bf(acc[mf][nf][r]);
    }
  }
#undef STA_
#undef STB_
#undef LDA_
#undef LDB01_
#undef LDB2_
#undef MM16
#undef MM8
}

// ---------------- 256^2 4-phase GEMM [R6-proven body] ----------------
template <int QM, int QN>
DEV void mmq(f32x4 (&acc)[8][4], const bf16x8 (&a)[4][2], const bf16x8 (&b)[2][2]) {
#pragma unroll
  for (int mf = 0; mf < 4; ++mf)
#pragma unroll
    for (int nf = 0; nf < 2; ++nf) {
      acc[QM * 4 + mf][QN * 2 + nf] = mfma_bf16(a[mf][0], b[nf][0], acc[QM * 4 + mf][QN * 2 + nf]);
      acc[QM * 4 + mf][QN * 2 + nf] = mfma_bf16(a[mf][1], b[nf][1], acc[QM * 4 + mf][QN * 2 + nf]);
    }
}

template <int EPI>
__global__ __launch_bounds__(512, 2) void gemm256(
    const u16* __restrict__ A, const u16* __restrict__ B0,
    void* __restrict__ outp, int M, int N, int K, int NT) {
  __shared__ u16 S[65536];
  const int tid = threadIdx.x;
  const int lane = tid & 63;
  const int wv = tid >> 6;
  const int wr = wv >> 2;
  const int wc = wv & 3;
  const int c16 = lane & 15, g4 = lane >> 4;

  int gx = gridDim.x;
  int nwg = gx * gridDim.y;
  int lin = blockIdx.x + gx * blockIdx.y;
  int swz = ((nwg & 7) == 0) ? ((lin & 7) * (nwg >> 3) + (lin >> 3)) : lin;
  const int bm = (swz / gx) * 256;
  const int bn = (swz % gx) * 256;

  const int sr = tid >> 2;
  const int sc2s = ((tid & 3) * 16) ^ (((sr >> 3) & 1) << 5);
  const int scol = sc2s >> 1;
  const u16* Asrc = A + (size_t)(bm + sr) * K + scol;
  const u16* Bsrc = B0 + (size_t)(bn + sr) * K + scol;
  const int ldst = wv * 512;

#define STA(buf, h, t) do { \
    const u16* _g = Asrc + (size_t)(h) * 128 * K + (t) * 64; \
    async16(_g,      &S[(buf) * 16384 + (h) * 8192 + ldst]); \
    async16(_g + 32, &S[(buf) * 16384 + (h) * 8192 + 4096 + ldst]); } while (0)
#define STB(buf, h, t) do { \
    const u16* _g = Bsrc + (size_t)(h) * 128 * K + (t) * 64; \
    async16(_g,      &S[32768 + (buf) * 16384 + (h) * 8192 + ldst]); \
    async16(_g + 32, &S[32768 + (buf) * 16384 + (h) * 8192 + 4096 + ldst]); } while (0)

  const int xr = (g4 * 8) ^ (((c16 >> 3) & 1) << 4);
  const int raOff = c16 * 32 + xr;
  const int abase0 = wr * 8192;
  const int bbase0 = 32768 + (wc >> 1) * 8192 + (wc & 1) * 2048;

#define LDA(buf, qm) do { _Pragma("unroll") \
    for (int mf = 0; mf < 4; ++mf) { \
      int _ro = (buf) * 16384 + abase0 + ((qm) * 64 + mf * 16) * 32 + raOff; \
      a[mf][0] = *(const bf16x8*)&S[_ro]; \
      a[mf][1] = *(const bf16x8*)&S[_ro + 4096]; } } while (0)
#define LDB(buf, qn, bq) do { _Pragma("unroll") \
    for (int nf = 0; nf < 2; ++nf) { \
      int _ro = (buf) * 16384 + bbase0 + ((qn) * 2 + nf) * 512 + raOff; \
      bq[nf][0] = *(const bf16x8*)&S[_ro]; \
      bq[nf][1] = *(const bf16x8*)&S[_ro + 4096]; } } while (0)

  f32x4 acc[8][4] = {};
  bf16x8 a[4][2], bq0[2][2], bq1[2][2];

  STB(0, 0, 0); STA(0, 0, 0); STB(0, 1, 0); STA(0, 1, 0);
  STB(1, 0, 1); STA(1, 0, 1);
  VMC(4); BARRIER();

  for (int kt = 0; kt < NT; ++kt) {
    const int buf = kt & 1, ob = buf ^ 1;
    const int t1 = (kt + 1 < NT) ? kt + 1 : NT - 1;
    const int t2 = (kt + 2 < NT) ? kt + 2 : NT - 1;
    LDA(buf, 0); LDB(buf, 0, bq0);
    STB(ob, 1, t1);
    BARRIER(); LGK0();
    __builtin_amdgcn_s_setprio(1); mmq<0, 0>(acc, a, bq0); __builtin_amdgcn_s_setprio(0);
    BARRIER();
    LDB(buf, 1, bq1);
    STA(ob, 1, t1);
    BARRIER(); LGK0();
    __builtin_amdgcn_s_setprio(1); mmq<0, 1>(acc, a, bq1); __builtin_amdgcn_s_setprio(0);
    BARRIER();
    LDA(buf, 1);
    STB(buf, 0, t2);
    BARRIER(); LGK0();
    __builtin_amdgcn_s_setprio(1); mmq<1, 0>(acc, a, bq0); __builtin_amdgcn_s_setprio(0);
    BARRIER();
    STA(buf, 0, t2);
    BARRIER();
    __builtin_amdgcn_s_setprio(1); mmq<1, 1>(acc, a, bq1); __builtin_amdgcn_s_setprio(0);
    VMC(4); BARRIER();
  }
  asm volatile("s_waitcnt vmcnt(0)" ::: "memory");

#pragma unroll
  for (int mf = 0; mf < 8; ++mf) {
    int row0 = bm + wr * 128 + mf * 16 + g4 * 4;
    if constexpr (EPI == 0) {
#pragma unroll
      for (int nf = 0; nf < 4; ++nf) {
        int col = bn + wc * 64 + nf * 16 + c16;
#pragma unroll
        for (int r = 0; r < 4; ++r)
          ((float*)outp)[(size_t)(row0 + r) * N + col] = acc[mf][nf][r];
      }
    } else {
      const int NH = N >> 1;
#pragma unroll
      for (int p = 0; p < 2; ++p) {
        int hid = ((bn + wc * 64) >> 1) + p * 16 + c16;
#pragma unroll
        for (int r = 0; r < 4; ++r) {
          float gg = acc[mf][2 * p][r];
          float uu = acc[mf][2 * p + 1][r];
          ((u16*)outp)[(size_t)(row0 + r) * NH + hid] = f2bf(gg * uu / (1.0f + __expf(-gg)));
        }
      }
    }
  }
#undef STA
#undef STB
#undef LDA
#undef LDB
}

// ---------------- flash attention, sliding window 512 [R6-proven body] ----------------
__global__ __launch_bounds__(256, 4) void attn_k(const u16* __restrict__ Q,
                                                 const u16* __restrict__ Kb,
                                                 const u16* __restrict__ VT,
                                                 u16* __restrict__ O) {
  __shared__ u16 KT[2 * 2048];
  __shared__ u16 VTl[2 * 2048];
  __shared__ float bsm[4][16];
  __shared__ u16 Plds[4][16 * 40];
  const int tid = threadIdx.x;
  const int lane = tid & 63;
  const int wv = tid >> 6;
  const int bh = blockIdx.y;
  const int q0b = blockIdx.x * 64;
  const int q0 = q0b + wv * 16;
  const int c16 = lane & 15;
  const int hi = lane >> 4;
  const u16* Qp = Q + ((size_t)bh * 2048 + q0) * 64;

  const bf16x8 qf0 = *(const bf16x8*)&Qp[c16 * 64 + hi * 8];
  const bf16x8 qf1 = *(const bf16x8*)&Qp[c16 * 64 + 32 + hi * 8];

  const int krow = tid >> 3;
  const int kcs = ((tid & 7) ^ (krow & 7)) * 8;
  const u16* Ksrc = Kb + (size_t)bh * 131072 + (size_t)krow * 64 + kcs;
  const int vrow = tid >> 2;
  const int vcs = ((tid & 3) ^ ((vrow >> 1) & 3)) * 8;
  const u16* Vsrc = VT + (size_t)bh * 131072 + (size_t)vrow * 2048 + vcs;
  const int wvb = wv * 512;

  f32x4 o[4] = {};
  float m = -30.0f;
  float psum = 0.0f;
  const float SCL = 0.125f * 1.4426950408889634f;
  int startb = q0b - 511;
  if (startb < 0) startb = 0;
  startb &= ~31;
  const int kgend = q0b + 32;
  u16* Pw = Plds[wv];
  float* bw = bsm[wv];

  const int xh0 = (hi ^ (c16 & 7)) * 8;
  const int xh4 = ((4 + hi) ^ (c16 & 7)) * 8;
  const int xv = (hi ^ ((c16 >> 1) & 3)) * 8;

  async16(Ksrc + (size_t)startb * 64, &KT[wvb]);
  async16(Vsrc + startb, &VTl[wvb]);

  int buf = 0;
  for (int kg = startb; kg <= kgend; kg += 32) {
    if (kg + 32 <= kgend) {
      async16(Ksrc + (size_t)(kg + 32) * 64, &KT[(buf ^ 1) * 2048 + wvb]);
      async16(Vsrc + (kg + 32), &VTl[(buf ^ 1) * 2048 + wvb]);
      VMC(2);
    } else {
      VMC(0);
    }
    BARRIER();
    if (kg <= q0 + 15 && kg >= q0 - 542) {
      const int kb = buf * 2048 + c16 * 64;
      bf16x8 k00 = *(const bf16x8*)&KT[kb + xh0];
      bf16x8 k01 = *(const bf16x8*)&KT[kb + xh4];
      bf16x8 k10 = *(const bf16x8*)&KT[kb + 1024 + xh0];
      bf16x8 k11 = *(const bf16x8*)&KT[kb + 1024 + xh4];
      bf16x8 vf[4];
#pragma unroll
      for (int n = 0; n < 4; ++n)
        vf[n] = *(const bf16x8*)&VTl[buf * 2048 + (n * 16 + c16) * 32 + xv];
      LGK0();

      f32x4 slo = {0.f, 0.f, 0.f, 0.f}, shi2 = {0.f, 0.f, 0.f, 0.f};
      __builtin_amdgcn_s_setprio(1);
      slo = mfma_bf16(k00, qf0, slo);
      slo = mfma_bf16(k01, qf1, slo);
      shi2 = mfma_bf16(k10, qf0, shi2);
      shi2 = mfma_bf16(k11, qf1, shi2);
      __builtin_amdgcn_s_setprio(0);

      float sc[8];
#pragma unroll
      for (int r = 0; r < 4; ++r) {
        sc[r] = slo[r] * SCL;
        sc[4 + r] = shi2[r] * SCL;
      }
      const bool inter = (kg + 31 <= q0) && (kg >= q0 - 496);
      if (!inter) {
        const int row = q0 + c16;
#pragma unroll
        for (int r = 0; r < 4; ++r) {
          int col = kg + hi * 4 + r;
          if (!(col <= row && col > row - 512)) sc[r] = -1e30f;
          int col2 = col + 16;
          if (!(col2 <= row && col2 > row - 512)) sc[4 + r] = -1e30f;
        }
      }
      float tmax = fmaxf(fmaxf(fmaxf(sc[0], sc[1]), fmaxf(sc[2], sc[3])),
                         fmaxf(fmaxf(sc[4], sc[5]), fmaxf(sc[6], sc[7])));
      tmax = fmaxf(tmax, __shfl_xor(tmax, 16));
      tmax = fmaxf(tmax, __shfl_xor(tmax, 32));
      if (__any(tmax > m + 8.0f)) {
        float mn = fmaxf(m, tmax);
        float corr = exp2f(m - mn);
        m = mn;
        psum *= corr;
        bw[c16] = corr;
        __builtin_amdgcn_wave_barrier();
        float cr[4];
#pragma unroll
        for (int r = 0; r < 4; ++r) cr[r] = bw[hi * 4 + r];
        __builtin_amdgcn_wave_barrier();
#pragma unroll
        for (int n = 0; n < 4; ++n)
#pragma unroll
          for (int r = 0; r < 4; ++r) o[n][r] *= cr[r];
      }
      float p[8];
#pragma unroll
      for (int i = 0; i < 8; ++i) p[i] = exp2f(sc[i] - m);
      psum += ((p[0] + p[1]) + (p[2] + p[3])) + ((p[4] + p[5]) + (p[6] + p[7]));

      uint2 wlo, whi2;
      wlo.x = packbf(p[0], p[1]);
      wlo.y = packbf(p[2], p[3]);
      whi2.x = packbf(p[4], p[5]);
      whi2.y = packbf(p[6], p[7]);
      *(uint2*)&Pw[c16 * 40 + hi * 4] = wlo;
      *(uint2*)&Pw[c16 * 40 + 16 + hi * 4] = whi2;
      __builtin_amdgcn_wave_barrier();
      bf16x8 pa = *(const bf16x8*)&Pw[c16 * 40 + hi * 8];
      __builtin_amdgcn_wave_barrier();
      __builtin_amdgcn_s_setprio(1);
#pragma unroll
      for (int n = 0; n < 4; ++n) o[n] = mfma_bf16(pa, vf[n], o[n]);
      __builtin_amdgcn_s_setprio(0);
    }
    BARRIER();
    buf ^= 1;
  }

  psum += __shfl_xor(psum, 16);
  psum += __shfl_xor(psum, 32);
  bw[c16] = psum;
  __builtin_amdgcn_wave_barrier();
  const int b = bh >> 4, h = bh & 15;
#pragma unroll
  for (int r = 0; r < 4; ++r) {
    float inv = 1.0f / bw[hi * 4 + r];
    int row = q0 + hi * 4 + r;
#pragma unroll
    for (int n = 0; n < 4; ++n)
      O[((size_t)(b * 2048 + row)) * 1024 + h * 64 + n * 16 + c16] = f2bf(o[n][r] * inv);
  }
}

// ---------------- host ----------------
extern "C" void kernel_launch(void* const* d_in, const int* in_sizes, int n_in,
                              void* d_out, int out_size, void* d_ws, size_t ws_size,
                              hipStream_t stream) {
  const float* x    = (const float*)d_in[0];
  const float* n1w  = (const float*)d_in[1];
  const float* n2w  = (const float*)d_in[2];
  const float* wqkv = (const float*)d_in[3];
  const float* qnw  = (const float*)d_in[4];
  const float* knw  = (const float*)d_in[5];
  const float* wo   = (const float*)d_in[6];
  const float* w1   = (const float*)d_in[7];
  const float* w3   = (const float*)d_in[8];
  const float* w2   = (const float*)d_in[9];
  float* out = (float*)d_out;
  char* ws = (char*)d_ws;

  u16*   wqkv_b = (u16*)(ws + 0);            // 6291456 B
  u16*   wo_b   = (u16*)(ws + 6291456);      // 2097152
  u16*   w13i   = (u16*)(ws + 8388608);      // 11534336  [5632][1024] interleaved
  u16*   w2p    = (u16*)(ws + 19922944);     // 5767168   [1024][2816]
  u16*   h_b    = (u16*)(ws + 25690112);     // 8388608   (aliased: attn out bf16)
  u16*   qkv_b  = (u16*)(ws + 34078720);     // 25165824  bf16 [4096][3072] (aliased: act_b)
  u16*   act_b  = (u16*)(ws + 34078720);     // 23068672  bf16 [4096][2816]
  u16*   Qb     = (u16*)(ws + 84410368);     // 8388608   (aliased: h2 bf16)
  u16*   Kb     = (u16*)(ws + 92798976);     // 8388608
  u16*   VTb    = (u16*)(ws + 101187584);    // 8388608
  float* x2f    = (float*)(ws + 109576192);  // 16777216 ; total 126353408
  u16*   attn_b = h_b;
  u16*   h2_b   = Qb;

  // weight prep
  cvt_bf16_k<<<3072, 256, 0, stream>>>(wqkv, wqkv_b, 786432);
  cvt_bf16_k<<<1024, 256, 0, stream>>>(wo, wo_b, 262144);
  w13_prep_k<<<5632, 256, 0, stream>>>(w1, w3, w13i, 1441792);
  pad_cols_k<<<2816, 256, 0, stream>>>(w2, w2p, 2730, 2816, 720896);

  // h = rmsnorm(x) -> bf16
  rmsnorm_cvt_k<<<4096, 256, 0, stream>>>(x, n1w, h_b);
  // qkv = h @ w_qkv^T -> bf16, 256x192 full-chip grid
  gemm192<<<dim3(16, 16), 512, 0, stream>>>(h_b, wqkv_b, qkv_b, 3072, 1024, 16);
  // q/k rmsnorm + rope ; V transpose
  qk_post_k<<<16384, 256, 0, stream>>>(qkv_b, qnw, knw, Qb, Kb);
  vtrans_k<<<dim3(32, 32), 256, 0, stream>>>(qkv_b, VTb);
  // attention
  attn_k<<<dim3(32, 32), 256, 0, stream>>>(Qb, Kb, VTb, attn_b);
  // x2 = x + attn @ w_o^T  -- pipelined 128^2, 8 waves
  gemm128p<1><<<dim3(8, 32), 512, 0, stream>>>(attn_b, wo_b, x, x2f, 4096, 1024, 1024, 16);
  // h2 = rmsnorm(x2) -> bf16
  rmsnorm_cvt_k<<<4096, 256, 0, stream>>>(x2f, n2w, h2_b);
  // act = silu(g)*u via interleaved single-B 256^2 GEMM [R6 body]
  gemm256<3><<<dim3(22, 16), 512, 0, stream>>>(h2_b, w13i, act_b, 4096, 5632, 1024, 16);
  // out = x2 + act @ w2^T  -- pipelined 128^2, 8 waves
  gemm128p<1><<<dim3(8, 32), 512, 0, stream>>>(act_b, w2p, x2f, out, 4096, 1024, 2816, 44);
}